// Round 1
// baseline (501.547 us; speedup 1.0000x reference)
//
#include <hip/hip_runtime.h>

// Forward kinematics, H36M 32-joint tree, B = 262144.
// One thread per batch element. Fully unrolled over joints (PARENTS is
// compile-time), so rot[]/pos[] scalarize to registers with ~3 live 3x3
// rotations max. Loads: 9 x float4 per 4-joint group (144B, 16B-aligned).
// Stores: 3 x float4 per group (12 floats = 4 joints' positions).

__global__ __launch_bounds__(256) void fk32_kernel(
    const float* __restrict__ angles,
    const float* __restrict__ offsets,
    float* __restrict__ out,
    int B)
{
    const int b = blockIdx.x * 256 + threadIdx.x;
    if (b >= B) return;

    constexpr int PAR[32] = {-1,0,1,2,3,4,0,6,7,8,9,0,11,12,13,14,
                             12,16,17,18,19,20,19,22,12,24,25,26,27,28,27,30};

    const float4* __restrict__ ap = reinterpret_cast<const float4*>(angles) + (size_t)b * 72u;
    float4* __restrict__ op = reinterpret_cast<float4*>(out) + (size_t)b * 24u;

    // Fully scalarized by SROA after unroll (all constant indices).
    float rot[32][3][3];
    float pos[32][3];

#pragma unroll
    for (int g = 0; g < 8; ++g) {
        // Stage this group's 4 joint matrices (36 floats) via 9 float4 loads.
        float a[36];
#pragma unroll
        for (int q = 0; q < 9; ++q) {
            const float4 v = ap[g * 9 + q];
            a[4*q+0] = v.x; a[4*q+1] = v.y; a[4*q+2] = v.z; a[4*q+3] = v.w;
        }

        float po[12];
#pragma unroll
        for (int jj = 0; jj < 4; ++jj) {
            const int j = g * 4 + jj;
            if (j == 0) {
#pragma unroll
                for (int i = 0; i < 3; ++i)
#pragma unroll
                    for (int l = 0; l < 3; ++l)
                        rot[0][i][l] = a[i*3 + l];
                pos[0][0] = 0.f; pos[0][1] = 0.f; pos[0][2] = 0.f;
            } else {
                const int p = PAR[j];
                // Uniform loads -> s_load; cached.
                const float o0 = offsets[j*3+0];
                const float o1 = offsets[j*3+1];
                const float o2 = offsets[j*3+2];
                // pos[j][l] = sum_k off[k] * rot[p][k][l] + pos[p][l]
#pragma unroll
                for (int l = 0; l < 3; ++l)
                    pos[j][l] = fmaf(o0, rot[p][0][l],
                               fmaf(o1, rot[p][1][l],
                               fmaf(o2, rot[p][2][l], pos[p][l])));
                // rot[j] = A_j @ rot[p]   (dead for leaf joints -> DCE)
#pragma unroll
                for (int i = 0; i < 3; ++i) {
                    const float a0 = a[jj*9 + i*3 + 0];
                    const float a1 = a[jj*9 + i*3 + 1];
                    const float a2 = a[jj*9 + i*3 + 2];
#pragma unroll
                    for (int l = 0; l < 3; ++l)
                        rot[j][i][l] = fmaf(a0, rot[p][0][l],
                                      fmaf(a1, rot[p][1][l],
                                           a2 * rot[p][2][l]));
                }
            }
#pragma unroll
            for (int l = 0; l < 3; ++l)
                po[jj*3 + l] = pos[j][l];
        }

        // 12 floats (4 joints x 3) -> 3 aligned float4 stores.
        op[g*3+0] = make_float4(po[0], po[1], po[2],  po[3]);
        op[g*3+1] = make_float4(po[4], po[5], po[6],  po[7]);
        op[g*3+2] = make_float4(po[8], po[9], po[10], po[11]);
    }
}

extern "C" void kernel_launch(void* const* d_in, const int* in_sizes, int n_in,
                              void* d_out, int out_size, void* d_ws, size_t ws_size,
                              hipStream_t stream) {
    const float* angles  = (const float*)d_in[0];
    const float* offsets = (const float*)d_in[1];
    float* out = (float*)d_out;
    const int B = in_sizes[0] / 288;   // [B, 32, 3, 3]
    const int block = 256;
    const int grid = (B + block - 1) / block;
    fk32_kernel<<<grid, block, 0, stream>>>(angles, offsets, out, B);
}

// Round 2
// 477.398 us; speedup vs baseline: 1.0506x; 1.0506x over previous
//
#include <hip/hip_runtime.h>

// Forward kinematics, H36M 32-joint tree, B = 262144.
// R2: (a) all 32 positions accumulate in registers; single contiguous burst
//     of 24 float4 stores at the end (fixes 2.45x write amplification from
//     temporally-scattered 48B partial-line writes).
//     (b) double-buffered register prefetch: group g+1's 9 float4 loads are
//     issued before group g's data is consumed, keeping 9-18 KB/wave in
//     flight instead of ~2-3 loads (fixes vmcnt serialization / MLP).

__global__ __launch_bounds__(256) void fk32_kernel(
    const float* __restrict__ angles,
    const float* __restrict__ offsets,
    float* __restrict__ out,
    int B)
{
    const int b = blockIdx.x * 256 + threadIdx.x;
    if (b >= B) return;

    constexpr int PAR[32] = {-1,0,1,2,3,4,0,6,7,8,9,0,11,12,13,14,
                             12,16,17,18,19,20,19,22,12,24,25,26,27,28,27,30};

    const float4* __restrict__ ap = reinterpret_cast<const float4*>(angles) + (size_t)b * 72u;
    float4* __restrict__ op = reinterpret_cast<float4*>(out) + (size_t)b * 24u;

    // Double-buffered group staging: 2 x 9 float4 = 72 VGPRs of load data.
    float4 buf[2][9];
#pragma unroll
    for (int q = 0; q < 9; ++q) buf[0][q] = ap[q];

    // Scalarized by SROA (all constant indices after full unroll).
    float rot[32][3][3];
    float pos[32][3];   // all 96 floats live to the end (they ARE the output)

#pragma unroll
    for (int g = 0; g < 8; ++g) {
        // Issue next group's loads FIRST, before any wait on this group's data.
        if (g < 7) {
#pragma unroll
            for (int q = 0; q < 9; ++q) buf[(g + 1) & 1][q] = ap[(g + 1) * 9 + q];
        }

        // Unpack current group's 36 floats.
        float a[36];
#pragma unroll
        for (int q = 0; q < 9; ++q) {
            const float4 v = buf[g & 1][q];
            a[4*q+0] = v.x; a[4*q+1] = v.y; a[4*q+2] = v.z; a[4*q+3] = v.w;
        }

#pragma unroll
        for (int jj = 0; jj < 4; ++jj) {
            const int j = g * 4 + jj;
            if (j == 0) {
#pragma unroll
                for (int i = 0; i < 3; ++i)
#pragma unroll
                    for (int l = 0; l < 3; ++l)
                        rot[0][i][l] = a[i*3 + l];
                pos[0][0] = 0.f; pos[0][1] = 0.f; pos[0][2] = 0.f;
            } else {
                const int p = PAR[j];
                // Uniform scalar loads (cached via K$).
                const float o0 = offsets[j*3+0];
                const float o1 = offsets[j*3+1];
                const float o2 = offsets[j*3+2];
#pragma unroll
                for (int l = 0; l < 3; ++l)
                    pos[j][l] = fmaf(o0, rot[p][0][l],
                               fmaf(o1, rot[p][1][l],
                               fmaf(o2, rot[p][2][l], pos[p][l])));
                // rot[j] dead for leaf joints -> DCE.
#pragma unroll
                for (int i = 0; i < 3; ++i) {
                    const float a0 = a[jj*9 + i*3 + 0];
                    const float a1 = a[jj*9 + i*3 + 1];
                    const float a2 = a[jj*9 + i*3 + 2];
#pragma unroll
                    for (int l = 0; l < 3; ++l)
                        rot[j][i][l] = fmaf(a0, rot[p][0][l],
                                      fmaf(a1, rot[p][1][l],
                                           a2 * rot[p][2][l]));
                }
            }
        }
    }

    // Single contiguous store burst: 24 float4 (384 B) per thread,
    // temporally tight so L2 write-combines full 64B lines (no RMW).
#pragma unroll
    for (int g = 0; g < 8; ++g) {
        op[g*3+0] = make_float4(pos[g*4+0][0], pos[g*4+0][1], pos[g*4+0][2], pos[g*4+1][0]);
        op[g*3+1] = make_float4(pos[g*4+1][1], pos[g*4+1][2], pos[g*4+2][0], pos[g*4+2][1]);
        op[g*3+2] = make_float4(pos[g*4+2][2], pos[g*4+3][0], pos[g*4+3][1], pos[g*4+3][2]);
    }
}

extern "C" void kernel_launch(void* const* d_in, const int* in_sizes, int n_in,
                              void* d_out, int out_size, void* d_ws, size_t ws_size,
                              hipStream_t stream) {
    const float* angles  = (const float*)d_in[0];
    const float* offsets = (const float*)d_in[1];
    float* out = (float*)d_out;
    const int B = in_sizes[0] / 288;   // [B, 32, 3, 3]
    const int block = 256;
    const int grid = (B + block - 1) / block;
    fk32_kernel<<<grid, block, 0, stream>>>(angles, offsets, out, B);
}

// Round 3
// 444.853 us; speedup vs baseline: 1.1274x; 1.0732x over previous
//
#include <hip/hip_runtime.h>

// Forward kinematics, H36M 32-joint tree, B = 262144.
// R3: coalesced input path. Each wave owns 64 consecutive batch elements.
// Per 4-joint group, 9 x global_load_lds(16B) DMA the 9216B tile straight
// into LDS in address order (runs of 144B -> ~18 lines/instr instead of 64
// divergent lines/instr), elem-major layout. Wave-synchronous double buffer
// with hand-placed s_waitcnt vmcnt(9) so the prefetch never drains (AITER
// pattern). Lanes read their own element via min-phase ds_read_b128.
// Positions accumulate in registers; one contiguous 384B store burst/thread.

#define ASM_VMCNT9() asm volatile("s_waitcnt vmcnt(9)" ::: "memory")
#define ASM_VMCNT0() asm volatile("s_waitcnt vmcnt(0)" ::: "memory")
#define ASM_LGKM0()  asm volatile("s_waitcnt lgkmcnt(0)" ::: "memory")

__global__ __launch_bounds__(256) void fk32_kernel(
    const float* __restrict__ angles,
    const float* __restrict__ offsets,
    float* __restrict__ out,
    int B)
{
    constexpr int PAR[32] = {-1,0,1,2,3,4,0,6,7,8,9,0,11,12,13,14,
                             12,16,17,18,19,20,19,22,12,24,25,26,27,28,27,30};

    const int wid   = threadIdx.x >> 6;
    const int lane  = threadIdx.x & 63;
    const int wbase = blockIdx.x * 256 + wid * 64;   // wave's first element
    const int b     = wbase + lane;                  // this thread's element

    // 2 buffers x 4 waves x 576 float4 = 73728 B -> 2 blocks/CU.
    __shared__ float4 lds[2][4][576];

    const float4* __restrict__ gbase =
        reinterpret_cast<const float4*>(angles) + (size_t)wbase * 72u;

    // Diagonal gather addresses: DMA iteration t, lane L fetches tile float4
    // #n (n = 64t+L) at global float4 (n/9)*72 + (n%9); lands at LDS slot n,
    // i.e. elem-major layout lds4[e*9+q]. Computed once, reused for all 8
    // groups (group g adds +9 float4s).
    const float4* gp[9];
#pragma unroll
    for (int t = 0; t < 9; ++t) {
        const int n = t * 64 + lane;
        const int e = n / 9;          // magic-mul
        const int q = n - e * 9;
        gp[t] = gbase + (e * 72 + q);
    }

    // Prologue: group 0 -> buffer 0.
#pragma unroll
    for (int t = 0; t < 9; ++t)
        __builtin_amdgcn_global_load_lds(
            (const __attribute__((address_space(1))) void*)(gp[t]),
            (__attribute__((address_space(3))) void*)(&lds[0][wid][t * 64]),
            16, 0, 0);

    float rot[32][3][3];
    float pos[32][3];

#pragma unroll
    for (int g = 0; g < 8; ++g) {
        if (g < 7) {
            // Buffer (g+1)&1 was last read two iterations ago; make sure those
            // ds_read results are in VGPRs before the DMA overwrites it.
            ASM_LGKM0();
#pragma unroll
            for (int t = 0; t < 9; ++t)
                __builtin_amdgcn_global_load_lds(
                    (const __attribute__((address_space(1))) void*)(gp[t] + 9 * (g + 1)),
                    (__attribute__((address_space(3))) void*)(&lds[(g + 1) & 1][wid][t * 64]),
                    16, 0, 0);
        }
        // Wait for THIS group's 9 DMAs only; keep the next group's in flight.
        if (g == 7) { ASM_VMCNT0(); } else { ASM_VMCNT9(); }

        // Own element's 36 floats: 9 x ds_read_b128, bank=(4*lane+4q)%32 ->
        // minimum-phase, conflict-free.
        float a[36];
#pragma unroll
        for (int q = 0; q < 9; ++q) {
            const float4 v = lds[g & 1][wid][lane * 9 + q];
            a[4*q+0] = v.x; a[4*q+1] = v.y; a[4*q+2] = v.z; a[4*q+3] = v.w;
        }

#pragma unroll
        for (int jj = 0; jj < 4; ++jj) {
            const int j = g * 4 + jj;
            if (j == 0) {
#pragma unroll
                for (int i = 0; i < 3; ++i)
#pragma unroll
                    for (int l = 0; l < 3; ++l)
                        rot[0][i][l] = a[i*3 + l];
                pos[0][0] = 0.f; pos[0][1] = 0.f; pos[0][2] = 0.f;
            } else {
                const int p = PAR[j];
                const float o0 = offsets[j*3+0];   // uniform -> s_load
                const float o1 = offsets[j*3+1];
                const float o2 = offsets[j*3+2];
#pragma unroll
                for (int l = 0; l < 3; ++l)
                    pos[j][l] = fmaf(o0, rot[p][0][l],
                               fmaf(o1, rot[p][1][l],
                               fmaf(o2, rot[p][2][l], pos[p][l])));
                // rot[j] dead for leaf joints -> DCE.
#pragma unroll
                for (int i = 0; i < 3; ++i) {
                    const float a0 = a[jj*9 + i*3 + 0];
                    const float a1 = a[jj*9 + i*3 + 1];
                    const float a2 = a[jj*9 + i*3 + 2];
#pragma unroll
                    for (int l = 0; l < 3; ++l)
                        rot[j][i][l] = fmaf(a0, rot[p][0][l],
                                      fmaf(a1, rot[p][1][l],
                                           a2 * rot[p][2][l]));
                }
            }
        }
    }

    // Contiguous 384 B store burst per thread; temporally tight so L2
    // write-combines full lines.
    float4* __restrict__ op = reinterpret_cast<float4*>(out) + (size_t)b * 24u;
#pragma unroll
    for (int g = 0; g < 8; ++g) {
        op[g*3+0] = make_float4(pos[g*4+0][0], pos[g*4+0][1], pos[g*4+0][2], pos[g*4+1][0]);
        op[g*3+1] = make_float4(pos[g*4+1][1], pos[g*4+1][2], pos[g*4+2][0], pos[g*4+2][1]);
        op[g*3+2] = make_float4(pos[g*4+2][2], pos[g*4+3][0], pos[g*4+3][1], pos[g*4+3][2]);
    }
}

extern "C" void kernel_launch(void* const* d_in, const int* in_sizes, int n_in,
                              void* d_out, int out_size, void* d_ws, size_t ws_size,
                              hipStream_t stream) {
    const float* angles  = (const float*)d_in[0];
    const float* offsets = (const float*)d_in[1];
    float* out = (float*)d_out;
    const int B = in_sizes[0] / 288;   // [B, 32, 3, 3], B % 256 == 0
    const int block = 256;
    const int grid = (B + block - 1) / block;
    fk32_kernel<<<grid, block, 0, stream>>>(angles, offsets, out, B);
}

// Round 4
// 433.812 us; speedup vs baseline: 1.1561x; 1.0255x over previous
//
#include <hip/hip_runtime.h>

// Forward kinematics, H36M 32-joint tree, B = 262144.
// R4: one wave per block (64 elems), fully wave-synchronous, zero barriers.
// Input:  diagonal global_load_lds DMA double-buffer (R3, proven) - group
//         g+1's 9 x 1KB DMAs stay in flight while computing group g.
// Output: NEW - positions staged in padded LDS (stride 13 float4: 8 lanes
//         cover all 32 banks), flushed wave-coalesced in two passes
//         (joints 0-15 after group 3, joints 16-31 after group 7). Each
//         elem chunk = 192 B = 3 aligned full lines -> no partial-line RMW,
//         16 full lines per 1KB store instr (vs 64 divergent lines before).
// LDS 31744 B -> 5 blocks/CU; 9 KB DMA in flight per wave = 45 KB/CU.

#define ASM_VMCNT(N) asm volatile("s_waitcnt vmcnt(" #N ")" ::: "memory")
#define ASM_LGKM0()  asm volatile("s_waitcnt lgkmcnt(0)" ::: "memory")

__global__ __launch_bounds__(64) void fk32_kernel(
    const float* __restrict__ angles,
    const float* __restrict__ offsets,
    float* __restrict__ out,
    int B)
{
    constexpr int PAR[32] = {-1,0,1,2,3,4,0,6,7,8,9,0,11,12,13,14,
                             12,16,17,18,19,20,19,22,12,24,25,26,27,28,27,30};

    const int lane  = threadIdx.x;          // 0..63 (one wave per block)
    const int wbase = blockIdx.x * 64;      // wave's first element

    __shared__ float4 lin[2][576];          // input double buffer, 18432 B
    __shared__ float4 lout[832];            // 64 elems x (12+1 pad), 13312 B

    const float4* __restrict__ gbase =
        reinterpret_cast<const float4*>(angles) + (size_t)wbase * 72u;
    float4* __restrict__ gout =
        reinterpret_cast<float4*>(out) + (size_t)wbase * 24u;

    // Diagonal gather: DMA instr t, lane L fetches tile float4 #n (n=64t+L)
    // at global float4 (n/9)*72 + (n%9); lands at LDS slot n (elem-major).
    const float4* gp[9];
#pragma unroll
    for (int t = 0; t < 9; ++t) {
        const int n = t * 64 + lane;
        const int e = n / 9;
        const int q = n - e * 9;
        gp[t] = gbase + (e * 72 + q);
    }

    // Prologue: group 0 -> buffer 0.
#pragma unroll
    for (int t = 0; t < 9; ++t)
        __builtin_amdgcn_global_load_lds(
            (const __attribute__((address_space(1))) void*)(gp[t]),
            (__attribute__((address_space(3))) void*)(&lin[0][t * 64]),
            16, 0, 0);

    float rot[32][3][3];
    float pos[32][3];

#pragma unroll
    for (int g = 0; g < 8; ++g) {
        if (g < 7) {
            // Ensure pending ds_reads from the buffer we're about to
            // overwrite (and flush-0's lout ds_reads) have landed in VGPRs.
            ASM_LGKM0();
#pragma unroll
            for (int t = 0; t < 9; ++t)
                __builtin_amdgcn_global_load_lds(
                    (const __attribute__((address_space(1))) void*)(gp[t] + 9 * (g + 1)),
                    (__attribute__((address_space(3))) void*)(&lin[(g + 1) & 1][t * 64]),
                    16, 0, 0);
        }
        // Wait for THIS group's 9 DMAs only (FIFO vmcnt retirement).
        // g==4: FIFO is [g4 x9 | flush0 stores x12 | g5 x9] -> all but the
        //       youngest 21 retired guarantees g4's DMAs are done.
        if (g == 7)      { ASM_VMCNT(0);  }
        else if (g == 4) { ASM_VMCNT(21); }
        else             { ASM_VMCNT(9);  }

        // Own element's 36 floats: 9 x ds_read_b128 (2-way bank alias: free).
        float a[36];
#pragma unroll
        for (int q = 0; q < 9; ++q) {
            const float4 v = lin[g & 1][lane * 9 + q];
            a[4*q+0] = v.x; a[4*q+1] = v.y; a[4*q+2] = v.z; a[4*q+3] = v.w;
        }

#pragma unroll
        for (int jj = 0; jj < 4; ++jj) {
            const int j = g * 4 + jj;
            if (j == 0) {
#pragma unroll
                for (int i = 0; i < 3; ++i)
#pragma unroll
                    for (int l = 0; l < 3; ++l)
                        rot[0][i][l] = a[i*3 + l];
                pos[0][0] = 0.f; pos[0][1] = 0.f; pos[0][2] = 0.f;
            } else {
                const int p = PAR[j];
                const float o0 = offsets[j*3+0];   // uniform -> s_load
                const float o1 = offsets[j*3+1];
                const float o2 = offsets[j*3+2];
#pragma unroll
                for (int l = 0; l < 3; ++l)
                    pos[j][l] = fmaf(o0, rot[p][0][l],
                               fmaf(o1, rot[p][1][l],
                               fmaf(o2, rot[p][2][l], pos[p][l])));
                // rot[j] dead for leaf joints -> DCE.
#pragma unroll
                for (int i = 0; i < 3; ++i) {
                    const float a0 = a[jj*9 + i*3 + 0];
                    const float a1 = a[jj*9 + i*3 + 1];
                    const float a2 = a[jj*9 + i*3 + 2];
#pragma unroll
                    for (int l = 0; l < 3; ++l)
                        rot[j][i][l] = fmaf(a0, rot[p][0][l],
                                      fmaf(a1, rot[p][1][l],
                                           a2 * rot[p][2][l]));
                }
            }
        }

        // Stash this group's 4 joint positions (12 floats = 3 float4) into
        // padded LDS; stride 13 f4 -> banks (52L)%32 = perfect 8-lane spread.
        {
            const int gg = g & 3;
            const int j0 = g * 4;
            lout[lane*13 + gg*3 + 0] = make_float4(pos[j0+0][0], pos[j0+0][1], pos[j0+0][2], pos[j0+1][0]);
            lout[lane*13 + gg*3 + 1] = make_float4(pos[j0+1][1], pos[j0+1][2], pos[j0+2][0], pos[j0+2][1]);
            lout[lane*13 + gg*3 + 2] = make_float4(pos[j0+2][2], pos[j0+3][0], pos[j0+3][1], pos[j0+3][2]);
        }

        // Flush pass 0 (joints 0-15) after group 3; pass 1 after group 7.
        if (g == 3 || g == 7) {
            const int h = (g == 3) ? 0 : 1;
#pragma unroll
            for (int s = 0; s < 12; ++s) {
                const int n = s * 64 + lane;     // wave-tile float4 index
                const int e = n / 12;
                const int q = n - e * 12;
                const float4 v = lout[e*13 + q];
                gout[e*24 + h*12 + q] = v;       // 192B-aligned full lines
            }
        }
    }
}

extern "C" void kernel_launch(void* const* d_in, const int* in_sizes, int n_in,
                              void* d_out, int out_size, void* d_ws, size_t ws_size,
                              hipStream_t stream) {
    const float* angles  = (const float*)d_in[0];
    const float* offsets = (const float*)d_in[1];
    float* out = (float*)d_out;
    const int B = in_sizes[0] / 288;   // [B, 32, 3, 3], B % 64 == 0
    const int block = 64;
    const int grid = B / block;
    fk32_kernel<<<grid, block, 0, stream>>>(angles, offsets, out, B);
}